// Round 17
// baseline (131.073 us; speedup 1.0000x reference)
//
#include <hip/hip_runtime.h>
#include <hip/hip_fp8.h>

#define N_NODES 100000
#define D 64
#define N_EDGES 1200000
#define NCB 3125             // buckets of 32 dst nodes (1:1 with agg blocks)
#define NBLK 256             // edge partition blocks
#define PAD 16               // pad per-bucket total counters to 64B lines
#define CHUNK ((N_EDGES + NBLK - 1) / NBLK)   // 4688 edges per block
#define CSRMAX 2048          // LDS edge buffer per bucket (mean 384, max ~500)

typedef __attribute__((ext_vector_type(8))) short short8v;   // 8 bf16 (MFMA frag)
typedef __attribute__((ext_vector_type(4))) float f32x4;

__device__ __forceinline__ unsigned short f2bf(float x) {
    unsigned int b = __float_as_uint(x);
    b += 0x7FFFu + ((b >> 16) & 1u);          // round-to-nearest-even
    return (unsigned short)(b >> 16);
}
__device__ __forceinline__ unsigned char ftofp8(float x) {
    __hip_fp8_e4m3 q(x);                      // OCP e4m3, RNE+saturate
    return (unsigned char)q.__x;
}
#if __has_builtin(__builtin_amdgcn_cvt_f32_fp8)
#define F8D(w, s) __builtin_amdgcn_cvt_f32_fp8((w), (s))
#else
__device__ __forceinline__ float f8dec(unsigned int w, unsigned int s) {
    __hip_fp8_e4m3 q; q.__x = (unsigned char)(w >> (8 * s));
    return (float)q;
}
#define F8D(w, s) f8dec((w), (s))
#endif

// ---------- pass 1: per-block bucket histogram + totals + fp8 table + wb ----------
__global__ __launch_bounds__(256) void bin_hist(
    const int* __restrict__ eidx, int* __restrict__ hist, int* __restrict__ totP,
    const float* __restrict__ feat, unsigned char* __restrict__ f8b,
    const float* __restrict__ W, ushort* __restrict__ wb)
{
    __shared__ int h[NCB];
    for (int i = threadIdx.x; i < NCB; i += 256) h[i] = 0;
    __syncthreads();
    const int blk = blockIdx.x;

    // W fragment table: wb[t][c4][lane][j] = bf16(W[32t+(lane>>4)*8+j][16c4+(lane&15)])
    if (blk < 32) {
        int g  = blk * 256 + threadIdx.x;     // 0..8191
        int j  = g & 7;
        int l  = (g >> 3) & 63;
        int c4 = (g >> 9) & 3;
        int tt = g >> 11;
        int k   = 32 * tt + ((l >> 4) << 3) + j;
        int col = 16 * c4 + (l & 15);
        wb[g] = f2bf(W[k * 64 + col]);
    }

    const int beg = blk * CHUNK;
    const int end = min(beg + CHUNK, N_EDGES);
    for (int e = beg + threadIdx.x; e < end; e += 256)
        atomicAdd(&h[eidx[N_EDGES + e] >> 5], 1);

    // fp8 conversion of the feature table (6.4MB gather table)
    const int total4 = N_NODES * D / 4;
    for (int i = blk * 256 + threadIdx.x; i < total4; i += NBLK * 256) {
        float4 v = ((const float4*)feat)[i];
        uchar4 o;
        o.x = ftofp8(v.x); o.y = ftofp8(v.y); o.z = ftofp8(v.z); o.w = ftofp8(v.w);
        ((uchar4*)f8b)[i] = o;
    }

    __syncthreads();
    for (int i = threadIdx.x; i < NCB; i += 256) {
        int v = h[i];
        hist[blk * NCB + i] = v;              // row-major, coalesced, single-writer
        if (v) atomicAdd(&totP[i * PAD], v);
    }
}

// ---------- pass 2: bucket bases + per-(block,bucket) run starts ----------
// XCD-bijective swizzle: consecutive buckets land on one XCD (L2 reuse of
// shared hist lines). runstart stored TRANSPOSED [i*256+blk]: coalesced write.
__global__ __launch_bounds__(256) void rstart(
    const int* __restrict__ totP, const int* __restrict__ hist,
    int* __restrict__ boff, int* __restrict__ runstart)
{
    __shared__ int red[256];
    __shared__ int pfx[256];
    __shared__ int bo_s;

    const int tid = threadIdx.x;
    // bijective XCD swizzle (m204): nwg=NCB, q=NCB/8, r=NCB%8
    const int q = NCB / 8, r = NCB % 8;
    const int xcd = blockIdx.x % 8, idx = blockIdx.x / 8;
    const int i = (xcd < r ? xcd * (q + 1) : r * (q + 1) + (xcd - r) * q) + idx;

    int p = 0;
    for (int j = tid; j < i; j += 256) p += totP[j * PAD];
    red[tid] = p;
    __syncthreads();
    for (int off = 128; off > 0; off >>= 1) {
        if (tid < off) red[tid] += red[tid + off];
        __syncthreads();
    }
    if (tid == 0) {
        bo_s = red[0];
        boff[i] = red[0];
        if (i == 0) boff[NCB] = N_EDGES;
    }
    __syncthreads();

    int v = hist[tid * NCB + i];
    pfx[tid] = v;
    __syncthreads();
    for (int off = 1; off < 256; off <<= 1) {
        int x = (tid >= off) ? pfx[tid - off] : 0;
        __syncthreads();
        pfx[tid] += x;
        __syncthreads();
    }
    runstart[i * 256 + tid] = bo_s + pfx[tid] - v;
}

// ---------- pass 3: deterministic scatter into per-block sub-ranges ----------
__global__ __launch_bounds__(256) void bin_fill(
    const int* __restrict__ eidx, const int* __restrict__ runstart,
    unsigned int* __restrict__ pairs)
{
    __shared__ int lcur[NCB];                 // 12.5 KB
    const int blk = blockIdx.x;
    for (int i = threadIdx.x; i < NCB; i += 256) lcur[i] = runstart[i * 256 + blk];
    __syncthreads();
    const int beg = blk * CHUNK;
    const int end = min(beg + CHUNK, N_EDGES);
    for (int e = beg + threadIdx.x; e < end; e += 256) {
        int src = eidx[e];
        int dst = eidx[N_EDGES + e];
        int pos = atomicAdd(&lcur[dst >> 5], 1);
        pairs[pos] = ((unsigned int)src << 5) | (unsigned int)(dst & 31);
    }
}

// ---------- fused LDS-sort + aggregate + MFMA linear: block = 32-node bucket ----------
// Sort: read own pairs segment (~384 edges), cnt[32]+scan -> LDS csr, degrees.
// Phase A: octet (8 lanes) per node, uint2 fp8 gathers, 8-deep; mean bf16 -> LDS.
// Phase B: 4 waves x 2 MFMA tiles; self-feats from f32 feat; B-frags from L2 wb.
#define MROW 72   // means row stride in ushorts (144B, 16B-aligned)
#define D8X(sel) (((F8D(w0.x,sel)+F8D(w1.x,sel))+(F8D(w2.x,sel)+F8D(w3.x,sel))) \
               + ((F8D(w4.x,sel)+F8D(w5.x,sel))+(F8D(w6.x,sel)+F8D(w7.x,sel))))
#define D8Y(sel) (((F8D(w0.y,sel)+F8D(w1.y,sel))+(F8D(w2.y,sel)+F8D(w3.y,sel))) \
               + ((F8D(w4.y,sel)+F8D(w5.y,sel))+(F8D(w6.y,sel)+F8D(w7.y,sel))))
#define D4X(sel) ((F8D(w0.x,sel)+F8D(w1.x,sel))+(F8D(w2.x,sel)+F8D(w3.x,sel)))
#define D4Y(sel) ((F8D(w0.y,sel)+F8D(w1.y,sel))+(F8D(w2.y,sel)+F8D(w3.y,sel)))
__global__ __launch_bounds__(256) void sage_fused(
    const unsigned char* __restrict__ f8b,
    const float* __restrict__ feat,
    const int* __restrict__ boff,
    const unsigned int* __restrict__ pairs,
    const ushort* __restrict__ wb,
    const float* __restrict__ bias,
    float* __restrict__ out)
{
    __shared__ int cnt[32];
    __shared__ int lofs[33];
    __shared__ int lcur2[32];
    __shared__ int csrL[CSRMAX];              // 8 KB
    __shared__ __attribute__((aligned(16))) ushort means[32 * MROW];

    const int tid = threadIdx.x;
    const int b   = blockIdx.x;
    const int n0  = b * 32;
    const int beg = boff[b];
    const int end = boff[b + 1];

    // ----- in-LDS counting sort of this bucket's edges -----
    if (tid < 32) cnt[tid] = 0;
    __syncthreads();
    for (int j = beg + tid; j < end; j += 256)
        atomicAdd(&cnt[pairs[j] & 31], 1);
    __syncthreads();
    if (tid == 0) {
        int run = 0;
        #pragma unroll
        for (int k = 0; k < 32; ++k) { lofs[k] = run; run += cnt[k]; }
        lofs[32] = run;
    }
    __syncthreads();
    if (tid < 32) lcur2[tid] = lofs[tid];
    __syncthreads();
    for (int j = beg + tid; j < end; j += 256) {
        unsigned int p = pairs[j];
        int pos = atomicAdd(&lcur2[p & 31], 1);
        if (pos < CSRMAX) csrL[pos] = (int)(p >> 5);
    }
    __syncthreads();

    // ----- Phase A: gather -----
    const int l    = tid & 7;                 // lane within octet (dims 8l..8l+7)
    const int node = tid >> 3;                // 0..31

    int ebeg = lofs[node];
    int eend = lofs[node + 1];
    const int deg = eend - ebeg;
    if (ebeg > CSRMAX) ebeg = CSRMAX;
    if (eend > CSRMAX) eend = CSRMAX;
    const uint2* g8 = (const uint2*)f8b;      // row = 8 uint2

    float s0=0.f,s1=0.f,s2=0.f,s3=0.f,s4=0.f,s5=0.f,s6=0.f,s7=0.f;
    int e = ebeg;
    for (; e + 8 <= eend; e += 8) {
        int i0=csrL[e+0], i1=csrL[e+1], i2=csrL[e+2], i3=csrL[e+3];
        int i4=csrL[e+4], i5=csrL[e+5], i6=csrL[e+6], i7=csrL[e+7];
        uint2 w0 = g8[(size_t)i0 * 8 + l];
        uint2 w1 = g8[(size_t)i1 * 8 + l];
        uint2 w2 = g8[(size_t)i2 * 8 + l];
        uint2 w3 = g8[(size_t)i3 * 8 + l];
        uint2 w4 = g8[(size_t)i4 * 8 + l];
        uint2 w5 = g8[(size_t)i5 * 8 + l];
        uint2 w6 = g8[(size_t)i6 * 8 + l];
        uint2 w7 = g8[(size_t)i7 * 8 + l];
        s0 += D8X(0); s1 += D8X(1); s2 += D8X(2); s3 += D8X(3);
        s4 += D8Y(0); s5 += D8Y(1); s6 += D8Y(2); s7 += D8Y(3);
    }
    for (; e + 4 <= eend; e += 4) {
        int i0=csrL[e+0], i1=csrL[e+1], i2=csrL[e+2], i3=csrL[e+3];
        uint2 w0 = g8[(size_t)i0 * 8 + l];
        uint2 w1 = g8[(size_t)i1 * 8 + l];
        uint2 w2 = g8[(size_t)i2 * 8 + l];
        uint2 w3 = g8[(size_t)i3 * 8 + l];
        s0 += D4X(0); s1 += D4X(1); s2 += D4X(2); s3 += D4X(3);
        s4 += D4Y(0); s5 += D4Y(1); s6 += D4Y(2); s7 += D4Y(3);
    }
    for (; e < eend; ++e) {
        uint2 w0 = g8[(size_t)csrL[e] * 8 + l];
        s0 += F8D(w0.x,0); s1 += F8D(w0.x,1); s2 += F8D(w0.x,2); s3 += F8D(w0.x,3);
        s4 += F8D(w0.y,0); s5 += F8D(w0.y,1); s6 += F8D(w0.y,2); s7 += F8D(w0.y,3);
    }

    float dg = (float)deg;
    dg = dg > 1.0f ? dg : 1.0f;
    float inv = 1.0f / dg;
    {
        ushort s[8] = { f2bf(s0*inv), f2bf(s1*inv), f2bf(s2*inv), f2bf(s3*inv),
                        f2bf(s4*inv), f2bf(s5*inv), f2bf(s6*inv), f2bf(s7*inv) };
        *(ushort4*)(means + node * MROW + l * 8)     = *(ushort4*)&s[0];
        *(ushort4*)(means + node * MROW + l * 8 + 4) = *(ushort4*)&s[4];
    }
    __syncthreads();

    // ----- Phase B: MFMA. wave wv: row-tile rt = wv>>1 (16 nodes), col pair wv&1 -----
    const int lane = tid & 63;
    const int wv   = tid >> 6;
    const int rt   = wv >> 1;
    const int cp   = wv & 1;
    const int kg   = lane >> 4;
    const int cl   = lane & 15;

    const float* frow = feat + (size_t)(n0 + rt * 16 + cl) * 64;
    f32x4 p0 = *(const f32x4*)(frow + kg * 8);
    f32x4 p1 = *(const f32x4*)(frow + kg * 8 + 4);
    f32x4 p2 = *(const f32x4*)(frow + 32 + kg * 8);
    f32x4 p3 = *(const f32x4*)(frow + 32 + kg * 8 + 4);
    short8v a0, a1;
    #pragma unroll
    for (int k = 0; k < 4; ++k) {
        a0[k]     = (short)f2bf(p0[k]);
        a0[k + 4] = (short)f2bf(p1[k]);
        a1[k]     = (short)f2bf(p2[k]);
        a1[k + 4] = (short)f2bf(p3[k]);
    }
    const ushort* mrow = means + (rt * 16 + cl) * MROW;
    short8v a2 = *(const short8v*)(mrow + kg * 8);
    short8v a3 = *(const short8v*)(mrow + 32 + kg * 8);

    const short8v* wv8 = (const short8v*)wb;   // B-frags straight from L2

    #pragma unroll
    for (int qq = 0; qq < 2; ++qq) {
        const int c4 = cp * 2 + qq;
        float bv = bias[c4 * 16 + cl];
        f32x4 acc = (f32x4){bv, bv, bv, bv};
        acc = __builtin_amdgcn_mfma_f32_16x16x32_bf16(
            a0, wv8[(0 * 4 + c4) * 64 + lane], acc, 0, 0, 0);
        acc = __builtin_amdgcn_mfma_f32_16x16x32_bf16(
            a1, wv8[(1 * 4 + c4) * 64 + lane], acc, 0, 0, 0);
        acc = __builtin_amdgcn_mfma_f32_16x16x32_bf16(
            a2, wv8[(2 * 4 + c4) * 64 + lane], acc, 0, 0, 0);
        acc = __builtin_amdgcn_mfma_f32_16x16x32_bf16(
            a3, wv8[(3 * 4 + c4) * 64 + lane], acc, 0, 0, 0);
        #pragma unroll
        for (int r = 0; r < 4; ++r)
            out[(size_t)(n0 + rt * 16 + kg * 4 + r) * 64 + c4 * 16 + cl] = acc[r];
    }
}

extern "C" void kernel_launch(void* const* d_in, const int* in_sizes, int n_in,
                              void* d_out, int out_size, void* d_ws, size_t ws_size,
                              hipStream_t stream) {
    const float* feat = (const float*)d_in[0];
    const int*   eidx = (const int*)d_in[1];
    const float* W    = (const float*)d_in[2];
    const float* bias = (const float*)d_in[3];
    float* out = (float*)d_out;

    // ws layout (~19 MB)
    int* hist     = (int*)d_ws;                        // NBLK*NCB (800000)
    int* totP     = hist + NBLK * NCB;                 // NCB*PAD (50000, memset)
    int* runstart = totP + NCB * PAD;                  // NCB*256 transposed (800000)
    int* boff     = runstart + NCB * 256;              // NCB+1 (+pad -> 3128)
    ushort* wb    = (ushort*)(boff + 3128);            // 8192 bf16
    unsigned int* pairs = (unsigned int*)(wb + 8192);  // N_EDGES
    unsigned char* f8b  = (unsigned char*)(pairs + N_EDGES);  // N_NODES*64 fp8

    hipMemsetAsync(totP, 0, (size_t)NCB * PAD * sizeof(int), stream);

    bin_hist<<<NBLK, 256, 0, stream>>>(eidx, hist, totP, feat, f8b, W, wb);
    rstart<<<NCB, 256, 0, stream>>>(totP, hist, boff, runstart);
    bin_fill<<<NBLK, 256, 0, stream>>>(eidx, runstart, pairs);
    sage_fused<<<NCB, 256, 0, stream>>>(f8b, feat, boff, pairs, wb, bias, out);
}

// Round 18
// 97.737 us; speedup vs baseline: 1.3411x; 1.3411x over previous
//
#include <hip/hip_runtime.h>
#include <hip/hip_fp8.h>

#define N_NODES 100000
#define D 64
#define N_EDGES 1200000
#define NCB 391              // coarse buckets of 256 dst nodes (PROVEN build chain)
#define NBLK 256             // partition blocks
#define PAD 16               // pad per-bucket total counters to 64B lines
#define CHUNK ((N_EDGES + NBLK - 1) / NBLK)   // 4688 edges per block
#define CSR2 768             // LDS edge buffer per 32-node child (mean 384, +6sigma ~502)

typedef __attribute__((ext_vector_type(8))) short short8v;   // 8 bf16 (MFMA frag)
typedef __attribute__((ext_vector_type(4))) float f32x4;

__device__ __forceinline__ unsigned short f2bf(float x) {
    unsigned int b = __float_as_uint(x);
    b += 0x7FFFu + ((b >> 16) & 1u);          // round-to-nearest-even
    return (unsigned short)(b >> 16);
}
__device__ __forceinline__ unsigned char ftofp8(float x) {
    __hip_fp8_e4m3 q(x);                      // OCP e4m3, RNE+saturate
    return (unsigned char)q.__x;
}
#if __has_builtin(__builtin_amdgcn_cvt_f32_fp8)
#define F8D(w, s) __builtin_amdgcn_cvt_f32_fp8((w), (s))
#else
__device__ __forceinline__ float f8dec(unsigned int w, unsigned int s) {
    __hip_fp8_e4m3 q; q.__x = (unsigned char)(w >> (8 * s));
    return (float)q;
}
#define F8D(w, s) f8dec((w), (s))
#endif

// ---------- pass 1: per-block coarse histogram + bucket totals + fp8 table + wb ----------
__global__ __launch_bounds__(256) void bin_hist(
    const int* __restrict__ eidx, int* __restrict__ hist, int* __restrict__ totP,
    const float* __restrict__ feat, unsigned char* __restrict__ f8b,
    const float* __restrict__ W, ushort* __restrict__ wb)
{
    __shared__ int h[NCB];
    for (int i = threadIdx.x; i < NCB; i += 256) h[i] = 0;
    __syncthreads();
    const int blk = blockIdx.x;

    // W fragment table: wb[t][c4][lane][j] = bf16(W[32t+(lane>>4)*8+j][16c4+(lane&15)])
    if (blk < 32) {
        int g  = blk * 256 + threadIdx.x;     // 0..8191
        int j  = g & 7;
        int l  = (g >> 3) & 63;
        int c4 = (g >> 9) & 3;
        int tt = g >> 11;
        int k   = 32 * tt + ((l >> 4) << 3) + j;
        int col = 16 * c4 + (l & 15);
        wb[g] = f2bf(W[k * 64 + col]);
    }

    const int beg = blk * CHUNK;
    const int end = min(beg + CHUNK, N_EDGES);
    for (int e = beg + threadIdx.x; e < end; e += 256)
        atomicAdd(&h[eidx[N_EDGES + e] >> 8], 1);

    // fp8 conversion of the feature table (6.4MB gather table)
    const int total4 = N_NODES * D / 4;
    for (int i = blk * 256 + threadIdx.x; i < total4; i += NBLK * 256) {
        float4 v = ((const float4*)feat)[i];
        uchar4 o;
        o.x = ftofp8(v.x); o.y = ftofp8(v.y); o.z = ftofp8(v.z); o.w = ftofp8(v.w);
        ((uchar4*)f8b)[i] = o;
    }

    __syncthreads();
    for (int i = threadIdx.x; i < NCB; i += 256) {
        int v = h[i];
        hist[blk * NCB + i] = v;
        if (v) atomicAdd(&totP[i * PAD], v);
    }
}

// ---------- pass 2: bucket bases + per-(block,bucket) run starts (parallel) ----------
__global__ __launch_bounds__(256) void rstart(
    const int* __restrict__ totP, const int* __restrict__ hist,
    int* __restrict__ boff, int* __restrict__ runstart)
{
    __shared__ int red[256];
    __shared__ int pfx[256];
    __shared__ int bo_s;

    const int tid = threadIdx.x;
    const int i   = blockIdx.x;

    int p = 0;
    for (int j = tid; j < i; j += 256) p += totP[j * PAD];
    red[tid] = p;
    __syncthreads();
    for (int off = 128; off > 0; off >>= 1) {
        if (tid < off) red[tid] += red[tid + off];
        __syncthreads();
    }
    if (tid == 0) {
        bo_s = red[0];
        boff[i] = red[0];
        if (i == 0) boff[NCB] = N_EDGES;
    }
    __syncthreads();

    int v = hist[tid * NCB + i];
    pfx[tid] = v;
    __syncthreads();
    for (int off = 1; off < 256; off <<= 1) {
        int x = (tid >= off) ? pfx[tid - off] : 0;
        __syncthreads();
        pfx[tid] += x;
        __syncthreads();
    }
    runstart[tid * NCB + i] = bo_s + pfx[tid] - v;
}

// ---------- pass 3: deterministic scatter into per-block sub-ranges ----------
__global__ __launch_bounds__(256) void bin_fill(
    const int* __restrict__ eidx, const int* __restrict__ runstart,
    unsigned int* __restrict__ pairs)
{
    __shared__ int lcur[NCB];
    const int blk = blockIdx.x;
    for (int i = threadIdx.x; i < NCB; i += 256) lcur[i] = runstart[blk * NCB + i];
    __syncthreads();
    const int beg = blk * CHUNK;
    const int end = min(beg + CHUNK, N_EDGES);
    for (int e = beg + threadIdx.x; e < end; e += 256) {
        int src = eidx[e];
        int dst = eidx[N_EDGES + e];
        int pos = atomicAdd(&lcur[dst >> 8], 1);
        pairs[pos] = ((unsigned int)src << 8) | (unsigned int)(dst & 255);
    }
}

// ---------- fused filter-sort + aggregate + MFMA linear: block = 32 nodes ----------
// 8 child blocks per 256-node bucket. Each filter-scans the parent's pairs
// segment (~3072 edges, L2-hot: 8 readers), counting-sorts its own ~384 edges
// into a 3KB LDS csr. Gather: octet per node, uint2 fp8, 8-deep. MFMA as r16.
#define MROW 72   // means row stride in ushorts (144B, 16B-aligned)
#define D8X(sel) (((F8D(w0.x,sel)+F8D(w1.x,sel))+(F8D(w2.x,sel)+F8D(w3.x,sel))) \
               + ((F8D(w4.x,sel)+F8D(w5.x,sel))+(F8D(w6.x,sel)+F8D(w7.x,sel))))
#define D8Y(sel) (((F8D(w0.y,sel)+F8D(w1.y,sel))+(F8D(w2.y,sel)+F8D(w3.y,sel))) \
               + ((F8D(w4.y,sel)+F8D(w5.y,sel))+(F8D(w6.y,sel)+F8D(w7.y,sel))))
#define D4X(sel) ((F8D(w0.x,sel)+F8D(w1.x,sel))+(F8D(w2.x,sel)+F8D(w3.x,sel)))
#define D4Y(sel) ((F8D(w0.y,sel)+F8D(w1.y,sel))+(F8D(w2.y,sel)+F8D(w3.y,sel)))
__global__ __launch_bounds__(256) void sage_fused(
    const unsigned char* __restrict__ f8b,
    const float* __restrict__ feat,
    const int* __restrict__ boff,
    const unsigned int* __restrict__ pairs,
    const ushort* __restrict__ wb,
    const float* __restrict__ bias,
    float* __restrict__ out)
{
    __shared__ int cnt[32];
    __shared__ int lofs[33];
    __shared__ int lcur2[32];
    __shared__ int csrL[CSR2];                // 3 KB
    __shared__ __attribute__((aligned(16))) ushort means[32 * MROW];

    const int tid = threadIdx.x;
    const int b   = blockIdx.x >> 3;          // parent bucket
    const int c   = blockIdx.x & 7;           // child (32-node slice)
    const int n0  = b * 256 + c * 32;
    if (n0 >= N_NODES) return;

    const int beg = boff[b];
    const int end = boff[b + 1];

    // ----- filtered in-LDS counting sort -----
    if (tid < 32) cnt[tid] = 0;
    __syncthreads();
    for (int j = beg + tid; j < end; j += 256) {
        unsigned int p = pairs[j];
        int ld = (int)(p & 255u);
        if ((ld >> 5) == c) atomicAdd(&cnt[ld & 31], 1);
    }
    __syncthreads();
    if (tid == 0) {
        int run = 0;
        #pragma unroll
        for (int k = 0; k < 32; ++k) { lofs[k] = run; run += cnt[k]; }
        lofs[32] = run;
    }
    __syncthreads();
    if (tid < 32) lcur2[tid] = lofs[tid];
    __syncthreads();
    for (int j = beg + tid; j < end; j += 256) {
        unsigned int p = pairs[j];
        int ld = (int)(p & 255u);
        if ((ld >> 5) == c) {
            int pos = atomicAdd(&lcur2[ld & 31], 1);
            if (pos < CSR2) csrL[pos] = (int)(p >> 8);
        }
    }
    __syncthreads();

    // ----- Phase A: gather -----
    const int l    = tid & 7;                 // lane within octet (dims 8l..8l+7)
    const int node = tid >> 3;                // 0..31

    int ebeg = lofs[node];
    int eend = lofs[node + 1];
    const int deg = eend - ebeg;
    if (ebeg > CSR2) ebeg = CSR2;
    if (eend > CSR2) eend = CSR2;
    const uint2* g8 = (const uint2*)f8b;      // row = 8 uint2

    float s0=0.f,s1=0.f,s2=0.f,s3=0.f,s4=0.f,s5=0.f,s6=0.f,s7=0.f;
    int e = ebeg;
    for (; e + 8 <= eend; e += 8) {
        int i0=csrL[e+0], i1=csrL[e+1], i2=csrL[e+2], i3=csrL[e+3];
        int i4=csrL[e+4], i5=csrL[e+5], i6=csrL[e+6], i7=csrL[e+7];
        uint2 w0 = g8[(size_t)i0 * 8 + l];
        uint2 w1 = g8[(size_t)i1 * 8 + l];
        uint2 w2 = g8[(size_t)i2 * 8 + l];
        uint2 w3 = g8[(size_t)i3 * 8 + l];
        uint2 w4 = g8[(size_t)i4 * 8 + l];
        uint2 w5 = g8[(size_t)i5 * 8 + l];
        uint2 w6 = g8[(size_t)i6 * 8 + l];
        uint2 w7 = g8[(size_t)i7 * 8 + l];
        s0 += D8X(0); s1 += D8X(1); s2 += D8X(2); s3 += D8X(3);
        s4 += D8Y(0); s5 += D8Y(1); s6 += D8Y(2); s7 += D8Y(3);
    }
    for (; e + 4 <= eend; e += 4) {
        int i0=csrL[e+0], i1=csrL[e+1], i2=csrL[e+2], i3=csrL[e+3];
        uint2 w0 = g8[(size_t)i0 * 8 + l];
        uint2 w1 = g8[(size_t)i1 * 8 + l];
        uint2 w2 = g8[(size_t)i2 * 8 + l];
        uint2 w3 = g8[(size_t)i3 * 8 + l];
        s0 += D4X(0); s1 += D4X(1); s2 += D4X(2); s3 += D4X(3);
        s4 += D4Y(0); s5 += D4Y(1); s6 += D4Y(2); s7 += D4Y(3);
    }
    for (; e < eend; ++e) {
        uint2 w0 = g8[(size_t)csrL[e] * 8 + l];
        s0 += F8D(w0.x,0); s1 += F8D(w0.x,1); s2 += F8D(w0.x,2); s3 += F8D(w0.x,3);
        s4 += F8D(w0.y,0); s5 += F8D(w0.y,1); s6 += F8D(w0.y,2); s7 += F8D(w0.y,3);
    }

    float dg = (float)deg;
    dg = dg > 1.0f ? dg : 1.0f;
    float inv = 1.0f / dg;
    {
        ushort s[8] = { f2bf(s0*inv), f2bf(s1*inv), f2bf(s2*inv), f2bf(s3*inv),
                        f2bf(s4*inv), f2bf(s5*inv), f2bf(s6*inv), f2bf(s7*inv) };
        *(ushort4*)(means + node * MROW + l * 8)     = *(ushort4*)&s[0];
        *(ushort4*)(means + node * MROW + l * 8 + 4) = *(ushort4*)&s[4];
    }
    __syncthreads();

    // ----- Phase B: MFMA. wave wv: row-tile rt = wv>>1 (16 nodes), col pair wv&1 -----
    const int lane = tid & 63;
    const int wv   = tid >> 6;
    const int rt   = wv >> 1;
    const int cp   = wv & 1;
    const int kg   = lane >> 4;
    const int cl   = lane & 15;

    const float* frow = feat + (size_t)(n0 + rt * 16 + cl) * 64;
    f32x4 p0 = *(const f32x4*)(frow + kg * 8);
    f32x4 p1 = *(const f32x4*)(frow + kg * 8 + 4);
    f32x4 p2 = *(const f32x4*)(frow + 32 + kg * 8);
    f32x4 p3 = *(const f32x4*)(frow + 32 + kg * 8 + 4);
    short8v a0, a1;
    #pragma unroll
    for (int k = 0; k < 4; ++k) {
        a0[k]     = (short)f2bf(p0[k]);
        a0[k + 4] = (short)f2bf(p1[k]);
        a1[k]     = (short)f2bf(p2[k]);
        a1[k + 4] = (short)f2bf(p3[k]);
    }
    const ushort* mrow = means + (rt * 16 + cl) * MROW;
    short8v a2 = *(const short8v*)(mrow + kg * 8);
    short8v a3 = *(const short8v*)(mrow + 32 + kg * 8);

    const short8v* wv8 = (const short8v*)wb;   // B-frags straight from L2

    #pragma unroll
    for (int qq = 0; qq < 2; ++qq) {
        const int c4 = cp * 2 + qq;
        float bv = bias[c4 * 16 + cl];
        f32x4 acc = (f32x4){bv, bv, bv, bv};
        acc = __builtin_amdgcn_mfma_f32_16x16x32_bf16(
            a0, wv8[(0 * 4 + c4) * 64 + lane], acc, 0, 0, 0);
        acc = __builtin_amdgcn_mfma_f32_16x16x32_bf16(
            a1, wv8[(1 * 4 + c4) * 64 + lane], acc, 0, 0, 0);
        acc = __builtin_amdgcn_mfma_f32_16x16x32_bf16(
            a2, wv8[(2 * 4 + c4) * 64 + lane], acc, 0, 0, 0);
        acc = __builtin_amdgcn_mfma_f32_16x16x32_bf16(
            a3, wv8[(3 * 4 + c4) * 64 + lane], acc, 0, 0, 0);
        #pragma unroll
        for (int r = 0; r < 4; ++r)
            out[(size_t)(n0 + rt * 16 + kg * 4 + r) * 64 + c4 * 16 + cl] = acc[r];
    }
}

extern "C" void kernel_launch(void* const* d_in, const int* in_sizes, int n_in,
                              void* d_out, int out_size, void* d_ws, size_t ws_size,
                              hipStream_t stream) {
    const float* feat = (const float*)d_in[0];
    const int*   eidx = (const int*)d_in[1];
    const float* W    = (const float*)d_in[2];
    const float* bias = (const float*)d_in[3];
    float* out = (float*)d_out;

    // ws layout
    int* hist     = (int*)d_ws;                        // NBLK*NCB (100096)
    int* totP     = hist + NBLK * NCB;                 // NCB*PAD (6256, memset)
    int* runstart = totP + NCB * PAD;                  // NBLK*NCB (100096)
    int* boff     = runstart + NBLK * NCB;             // NCB+1 (+pad -> 396)
    ushort* wb    = (ushort*)(boff + 396);             // 8192 bf16
    unsigned int* pairs = (unsigned int*)(wb + 8192);  // N_EDGES
    unsigned char* f8b  = (unsigned char*)(pairs + N_EDGES);  // N_NODES*64 fp8

    hipMemsetAsync(totP, 0, (size_t)NCB * PAD * sizeof(int), stream);

    bin_hist<<<NBLK, 256, 0, stream>>>(eidx, hist, totP, feat, f8b, W, wb);
    rstart<<<NCB, 256, 0, stream>>>(totP, hist, boff, runstart);
    bin_fill<<<NBLK, 256, 0, stream>>>(eidx, runstart, pairs);
    sage_fused<<<NCB * 8, 256, 0, stream>>>(f8b, feat, boff, pairs, wb, bias, out);
}

// Round 19
// 86.535 us; speedup vs baseline: 1.5147x; 1.1294x over previous
//
#include <hip/hip_runtime.h>
#include <hip/hip_fp8.h>

#define N_NODES 100000
#define D 64
#define N_EDGES 1200000
#define NCB 391              // coarse buckets of 256 dst nodes (PROVEN build chain)
#define NBLK 256             // partition blocks
#define PAD 16               // pad per-bucket total counters to 64B lines
#define CHUNK ((N_EDGES + NBLK - 1) / NBLK)   // 4688 edges per block
#define CSRMAX 3584          // LDS edge buffer per bucket (mean 3072, +6sigma ~3400)

typedef __attribute__((ext_vector_type(8))) short short8v;   // 8 bf16 (MFMA frag)
typedef __attribute__((ext_vector_type(4))) float f32x4;

__device__ __forceinline__ unsigned short f2bf(float x) {
    unsigned int b = __float_as_uint(x);
    b += 0x7FFFu + ((b >> 16) & 1u);          // round-to-nearest-even
    return (unsigned short)(b >> 16);
}
__device__ __forceinline__ unsigned char ftofp8(float x) {
    __hip_fp8_e4m3 q(x);                      // OCP e4m3, RNE+saturate
    return (unsigned char)q.__x;
}
#if __has_builtin(__builtin_amdgcn_cvt_f32_fp8)
#define F8D(w, s) __builtin_amdgcn_cvt_f32_fp8((w), (s))
#else
__device__ __forceinline__ float f8dec(unsigned int w, unsigned int s) {
    __hip_fp8_e4m3 q; q.__x = (unsigned char)(w >> (8 * s));
    return (float)q;
}
#define F8D(w, s) f8dec((w), (s))
#endif

// ---------- pass 1: per-block coarse histogram + bucket totals + fp8 table + wb ----------
__global__ __launch_bounds__(256) void bin_hist(
    const int* __restrict__ eidx, int* __restrict__ hist, int* __restrict__ totP,
    const float* __restrict__ feat, unsigned char* __restrict__ f8b,
    const float* __restrict__ W, ushort* __restrict__ wb)
{
    __shared__ int h[NCB];
    for (int i = threadIdx.x; i < NCB; i += 256) h[i] = 0;
    __syncthreads();
    const int blk = blockIdx.x;

    // W fragment table: wb[t][c4][lane][j] = bf16(W[32t+(lane>>4)*8+j][16c4+(lane&15)])
    if (blk < 32) {
        int g  = blk * 256 + threadIdx.x;     // 0..8191
        int j  = g & 7;
        int l  = (g >> 3) & 63;
        int c4 = (g >> 9) & 3;
        int tt = g >> 11;
        int k   = 32 * tt + ((l >> 4) << 3) + j;
        int col = 16 * c4 + (l & 15);
        wb[g] = f2bf(W[k * 64 + col]);
    }

    const int beg = blk * CHUNK;
    const int end = min(beg + CHUNK, N_EDGES);
    for (int e = beg + threadIdx.x; e < end; e += 256)
        atomicAdd(&h[eidx[N_EDGES + e] >> 8], 1);

    // fp8 conversion of the feature table (6.4MB gather table)
    const int total4 = N_NODES * D / 4;
    for (int i = blk * 256 + threadIdx.x; i < total4; i += NBLK * 256) {
        float4 v = ((const float4*)feat)[i];
        uchar4 o;
        o.x = ftofp8(v.x); o.y = ftofp8(v.y); o.z = ftofp8(v.z); o.w = ftofp8(v.w);
        ((uchar4*)f8b)[i] = o;
    }

    __syncthreads();
    for (int i = threadIdx.x; i < NCB; i += 256) {
        int v = h[i];
        hist[blk * NCB + i] = v;
        if (v) atomicAdd(&totP[i * PAD], v);
    }
}

// ---------- pass 2: bucket bases + per-(block,bucket) run starts (parallel) ----------
__global__ __launch_bounds__(256) void rstart(
    const int* __restrict__ totP, const int* __restrict__ hist,
    int* __restrict__ boff, int* __restrict__ runstart)
{
    __shared__ int red[256];
    __shared__ int pfx[256];
    __shared__ int bo_s;

    const int tid = threadIdx.x;
    const int i   = blockIdx.x;

    int p = 0;
    for (int j = tid; j < i; j += 256) p += totP[j * PAD];
    red[tid] = p;
    __syncthreads();
    for (int off = 128; off > 0; off >>= 1) {
        if (tid < off) red[tid] += red[tid + off];
        __syncthreads();
    }
    if (tid == 0) {
        bo_s = red[0];
        boff[i] = red[0];
        if (i == 0) boff[NCB] = N_EDGES;
    }
    __syncthreads();

    int v = hist[tid * NCB + i];
    pfx[tid] = v;
    __syncthreads();
    for (int off = 1; off < 256; off <<= 1) {
        int x = (tid >= off) ? pfx[tid - off] : 0;
        __syncthreads();
        pfx[tid] += x;
        __syncthreads();
    }
    runstart[tid * NCB + i] = bo_s + pfx[tid] - v;
}

// ---------- pass 3: deterministic scatter into per-block sub-ranges ----------
__global__ __launch_bounds__(256) void bin_fill(
    const int* __restrict__ eidx, const int* __restrict__ runstart,
    unsigned int* __restrict__ pairs)
{
    __shared__ int lcur[NCB];
    const int blk = blockIdx.x;
    for (int i = threadIdx.x; i < NCB; i += 256) lcur[i] = runstart[blk * NCB + i];
    __syncthreads();
    const int beg = blk * CHUNK;
    const int end = min(beg + CHUNK, N_EDGES);
    for (int e = beg + threadIdx.x; e < end; e += 256) {
        int src = eidx[e];
        int dst = eidx[N_EDGES + e];
        int pos = atomicAdd(&lcur[dst >> 8], 1);
        pairs[pos] = ((unsigned int)src << 8) | (unsigned int)(dst & 255);
    }
}

// ---------- fused sort + aggregate + MFMA: one 512-thread block per bucket ----------
// Sort: bucket's ~3072 edges read ONCE -> cnt[256] + scan -> 14KB LDS csr.
// Then 4 groups of 64 nodes: octet-per-node fp8 gather -> means LDS -> MFMA.
#define MROW 72   // means row stride in ushorts (144B, 16B-aligned)
#define D8X(sel) (((F8D(w0.x,sel)+F8D(w1.x,sel))+(F8D(w2.x,sel)+F8D(w3.x,sel))) \
               + ((F8D(w4.x,sel)+F8D(w5.x,sel))+(F8D(w6.x,sel)+F8D(w7.x,sel))))
#define D8Y(sel) (((F8D(w0.y,sel)+F8D(w1.y,sel))+(F8D(w2.y,sel)+F8D(w3.y,sel))) \
               + ((F8D(w4.y,sel)+F8D(w5.y,sel))+(F8D(w6.y,sel)+F8D(w7.y,sel))))
#define D4X(sel) ((F8D(w0.x,sel)+F8D(w1.x,sel))+(F8D(w2.x,sel)+F8D(w3.x,sel)))
#define D4Y(sel) ((F8D(w0.y,sel)+F8D(w1.y,sel))+(F8D(w2.y,sel)+F8D(w3.y,sel)))
__global__ __launch_bounds__(512) void sage_fused(
    const unsigned char* __restrict__ f8b,
    const float* __restrict__ feat,
    const int* __restrict__ boff,
    const unsigned int* __restrict__ pairs,
    const ushort* __restrict__ wb,
    const float* __restrict__ bias,
    float* __restrict__ out)
{
    __shared__ int cnt[256];
    __shared__ int pfx[256];
    __shared__ int lofs[257];
    __shared__ int lcur[256];
    __shared__ int csrL[CSRMAX];              // 14 KB
    __shared__ __attribute__((aligned(16))) ushort means[64 * MROW];  // 9.2 KB

    const int tid  = threadIdx.x;
    const int b    = blockIdx.x;
    const int base = b * 256;
    const int beg  = boff[b];
    const int end  = boff[b + 1];

    // ----- in-LDS counting sort (single read of the bucket segment) -----
    if (tid < 256) cnt[tid] = 0;
    __syncthreads();
    for (int j = beg + tid; j < end; j += 512)
        atomicAdd(&cnt[pairs[j] & 255], 1);
    __syncthreads();
    if (tid < 256) pfx[tid] = cnt[tid];
    __syncthreads();
    for (int off = 1; off < 256; off <<= 1) {
        int x = 0;
        if (tid < 256 && tid >= off) x = pfx[tid - off];
        __syncthreads();
        if (tid < 256) pfx[tid] += x;
        __syncthreads();
    }
    if (tid < 256) {
        int ex = pfx[tid] - cnt[tid];
        lofs[tid] = ex;
        lcur[tid] = ex;
    }
    if (tid == 0) lofs[256] = end - beg;
    __syncthreads();
    for (int j = beg + tid; j < end; j += 512) {
        unsigned int p = pairs[j];
        int pos = atomicAdd(&lcur[p & 255], 1);
        if (pos < CSRMAX) csrL[pos] = (int)(p >> 8);
    }
    __syncthreads();

    // ----- 4 groups of 64 nodes: gather + MFMA -----
    const int l    = tid & 7;                 // lane within octet (dims 8l..8l+7)
    const int gn8  = tid >> 3;                // node within group, 0..63
    const uint2* g8 = (const uint2*)f8b;      // fp8 row = 8 uint2
    const short8v* wv8 = (const short8v*)wb;

    const int lane = tid & 63;
    const int wv   = tid >> 6;                // wave 0..7
    const int rt   = wv >> 1;                 // row tile 0..3
    const int cp   = wv & 1;                  // col pair
    const int kg   = lane >> 4;
    const int cl   = lane & 15;

    #pragma unroll 1
    for (int g = 0; g < 4; ++g) {
        const int ln = g * 64 + gn8;          // local node 0..255
        int ebeg = lofs[ln];
        int eend = lofs[ln + 1];
        const int deg = eend - ebeg;
        if (ebeg > CSRMAX) ebeg = CSRMAX;
        if (eend > CSRMAX) eend = CSRMAX;

        float s0=0.f,s1=0.f,s2=0.f,s3=0.f,s4=0.f,s5=0.f,s6=0.f,s7=0.f;
        int e = ebeg;
        for (; e + 8 <= eend; e += 8) {
            int i0=csrL[e+0], i1=csrL[e+1], i2=csrL[e+2], i3=csrL[e+3];
            int i4=csrL[e+4], i5=csrL[e+5], i6=csrL[e+6], i7=csrL[e+7];
            uint2 w0 = g8[(size_t)i0 * 8 + l];
            uint2 w1 = g8[(size_t)i1 * 8 + l];
            uint2 w2 = g8[(size_t)i2 * 8 + l];
            uint2 w3 = g8[(size_t)i3 * 8 + l];
            uint2 w4 = g8[(size_t)i4 * 8 + l];
            uint2 w5 = g8[(size_t)i5 * 8 + l];
            uint2 w6 = g8[(size_t)i6 * 8 + l];
            uint2 w7 = g8[(size_t)i7 * 8 + l];
            s0 += D8X(0); s1 += D8X(1); s2 += D8X(2); s3 += D8X(3);
            s4 += D8Y(0); s5 += D8Y(1); s6 += D8Y(2); s7 += D8Y(3);
        }
        for (; e + 4 <= eend; e += 4) {
            int i0=csrL[e+0], i1=csrL[e+1], i2=csrL[e+2], i3=csrL[e+3];
            uint2 w0 = g8[(size_t)i0 * 8 + l];
            uint2 w1 = g8[(size_t)i1 * 8 + l];
            uint2 w2 = g8[(size_t)i2 * 8 + l];
            uint2 w3 = g8[(size_t)i3 * 8 + l];
            s0 += D4X(0); s1 += D4X(1); s2 += D4X(2); s3 += D4X(3);
            s4 += D4Y(0); s5 += D4Y(1); s6 += D4Y(2); s7 += D4Y(3);
        }
        for (; e < eend; ++e) {
            uint2 w0 = g8[(size_t)csrL[e] * 8 + l];
            s0 += F8D(w0.x,0); s1 += F8D(w0.x,1); s2 += F8D(w0.x,2); s3 += F8D(w0.x,3);
            s4 += F8D(w0.y,0); s5 += F8D(w0.y,1); s6 += F8D(w0.y,2); s7 += F8D(w0.y,3);
        }

        float dg = (float)deg;
        dg = dg > 1.0f ? dg : 1.0f;
        float inv = 1.0f / dg;
        {
            ushort s[8] = { f2bf(s0*inv), f2bf(s1*inv), f2bf(s2*inv), f2bf(s3*inv),
                            f2bf(s4*inv), f2bf(s5*inv), f2bf(s6*inv), f2bf(s7*inv) };
            *(ushort4*)(means + gn8 * MROW + l * 8)     = *(ushort4*)&s[0];
            *(ushort4*)(means + gn8 * MROW + l * 8 + 4) = *(ushort4*)&s[4];
        }
        __syncthreads();

        // ----- MFMA for this 64-node group -----
        const int n0g = base + g * 64;
        const int nA  = n0g + rt * 16 + cl;
        const int nAc = nA < N_NODES ? nA : N_NODES - 1;
        const float* frow = feat + (size_t)nAc * 64;
        f32x4 p0 = *(const f32x4*)(frow + kg * 8);
        f32x4 p1 = *(const f32x4*)(frow + kg * 8 + 4);
        f32x4 p2 = *(const f32x4*)(frow + 32 + kg * 8);
        f32x4 p3 = *(const f32x4*)(frow + 32 + kg * 8 + 4);
        short8v a0, a1;
        #pragma unroll
        for (int k = 0; k < 4; ++k) {
            a0[k]     = (short)f2bf(p0[k]);
            a0[k + 4] = (short)f2bf(p1[k]);
            a1[k]     = (short)f2bf(p2[k]);
            a1[k + 4] = (short)f2bf(p3[k]);
        }
        const ushort* mrow = means + (rt * 16 + cl) * MROW;
        short8v a2 = *(const short8v*)(mrow + kg * 8);
        short8v a3 = *(const short8v*)(mrow + 32 + kg * 8);

        #pragma unroll
        for (int qq = 0; qq < 2; ++qq) {
            const int c4 = cp * 2 + qq;
            float bv = bias[c4 * 16 + cl];
            f32x4 acc = (f32x4){bv, bv, bv, bv};
            acc = __builtin_amdgcn_mfma_f32_16x16x32_bf16(
                a0, wv8[(0 * 4 + c4) * 64 + lane], acc, 0, 0, 0);
            acc = __builtin_amdgcn_mfma_f32_16x16x32_bf16(
                a1, wv8[(1 * 4 + c4) * 64 + lane], acc, 0, 0, 0);
            acc = __builtin_amdgcn_mfma_f32_16x16x32_bf16(
                a2, wv8[(2 * 4 + c4) * 64 + lane], acc, 0, 0, 0);
            acc = __builtin_amdgcn_mfma_f32_16x16x32_bf16(
                a3, wv8[(3 * 4 + c4) * 64 + lane], acc, 0, 0, 0);
            #pragma unroll
            for (int r = 0; r < 4; ++r) {
                int orow = n0g + rt * 16 + kg * 4 + r;
                if (orow < N_NODES)
                    out[(size_t)orow * 64 + c4 * 16 + cl] = acc[r];
            }
        }
        __syncthreads();   // means reused next group
    }
}

extern "C" void kernel_launch(void* const* d_in, const int* in_sizes, int n_in,
                              void* d_out, int out_size, void* d_ws, size_t ws_size,
                              hipStream_t stream) {
    const float* feat = (const float*)d_in[0];
    const int*   eidx = (const int*)d_in[1];
    const float* W    = (const float*)d_in[2];
    const float* bias = (const float*)d_in[3];
    float* out = (float*)d_out;

    // ws layout
    int* hist     = (int*)d_ws;                        // NBLK*NCB (100096)
    int* totP     = hist + NBLK * NCB;                 // NCB*PAD (6256, memset)
    int* runstart = totP + NCB * PAD;                  // NBLK*NCB (100096)
    int* boff     = runstart + NBLK * NCB;             // NCB+1 (+pad -> 396)
    ushort* wb    = (ushort*)(boff + 396);             // 8192 bf16
    unsigned int* pairs = (unsigned int*)(wb + 8192);  // N_EDGES
    unsigned char* f8b  = (unsigned char*)(pairs + N_EDGES);  // N_NODES*64 fp8

    hipMemsetAsync(totP, 0, (size_t)NCB * PAD * sizeof(int), stream);

    bin_hist<<<NBLK, 256, 0, stream>>>(eidx, hist, totP, feat, f8b, W, wb);
    rstart<<<NCB, 256, 0, stream>>>(totP, hist, boff, runstart);
    bin_fill<<<NBLK, 256, 0, stream>>>(eidx, runstart, pairs);
    sage_fused<<<NCB, 512, 0, stream>>>(f8b, feat, boff, pairs, wb, bias, out);
}